// Round 6
// baseline (52.610 us; speedup 1.0000x reference)
//
#include <hip/hip_runtime.h>

// B rows; input row: [tx, ty, tz, ax, ay, az] (f32)
// output row (12 f32): [M00-1, M01, M02, tx, M10, M11-1, M12, ty, M20, M21, M22-1, tz]
// where M = Rx(ax) @ Ry(ay) @ Rz(az), expanded in closed form.
//
// Round-5 structure, halved per-block footprint for occupancy:
//   BLOCK=256 threads, RPB=256 rows (1 row/thread), LDS = 18 KB
//   -> 8 blocks/CU (LDS-capped), 2048 threads/CU = 100% occupancy.
//   P1 : coalesced float4 global->LDS (384 vectors, 1.5/thread)
//   P2a: 3x b64 read own row (stride 24B)
//   P2b: 3x b128 swizzled LDS write (stride 48B, ~2-way)
//   P3 : 3x float4/thread swizzled LDS read -> coalesced global store

#define BLOCK 256
#define RPB   256   // rows per block (1 per thread)

__device__ __forceinline__ int swz(int i) { return i ^ ((i >> 3) & 7); }

__global__ __launch_bounds__(BLOCK) void affine_to_matrix_staged(
    const float* __restrict__ in, float* __restrict__ out) {
    __shared__ float s_in[RPB * 6];    // 6 KB
    __shared__ float s_out[RPB * 12];  // 12 KB

    const int tid = threadIdx.x;
    const size_t rowBase = (size_t)blockIdx.x * RPB;
    const float4* gin  = reinterpret_cast<const float4*>(in  + rowBase * 6);
    float4*       gout = reinterpret_cast<float4*>(out + rowBase * 12);

    // P1: coalesced global -> LDS (384 float4; second pass half-masked)
    float4* s_in4 = reinterpret_cast<float4*>(s_in);
    {
        s_in4[tid] = gin[tid];
        int g = tid + BLOCK;
        if (g < RPB * 6 / 4) s_in4[g] = gin[g];
    }
    __syncthreads();

    // P2a: read own row (3x float2, 8B-aligned at 24B stride)
    const float2* myin = reinterpret_cast<const float2*>(s_in + tid * 6);
    float2 a = myin[0], b = myin[1], c = myin[2];
    float tx = a.x, ty = a.y, tz = b.x;
    float ax = b.y, ay = c.x, az = c.y;

    // P2b: compute + swizzled LDS write (float4 index 3t+q)
    float sx, cx, sy, cy, sz, cz;
    __sincosf(ax, &sx, &cx);
    __sincosf(ay, &sy, &cy);
    __sincosf(az, &sz, &cz);
    float sxsy = sx * sy;
    float cxsy = cx * sy;
    float4* s_out4 = reinterpret_cast<float4*>(s_out);
    int base = tid * 3;
    s_out4[swz(base + 0)] = make_float4(cy * cz - 1.0f,      -cy * sz,                    sy,             tx);
    s_out4[swz(base + 1)] = make_float4(cx * sz + sxsy * cz, cx * cz - sxsy * sz - 1.0f,  -sx * cy,       ty);
    s_out4[swz(base + 2)] = make_float4(sx * sz - cxsy * cz, sx * cz + cxsy * sz,         cx * cy - 1.0f, tz);
    __syncthreads();

    // P3: swizzled LDS read -> coalesced global store (768 float4, 3/thread)
    #pragma unroll
    for (int k = 0; k < 3; ++k) {
        int g = tid + k * BLOCK;
        gout[g] = s_out4[swz(g)];
    }
}

// Tail path: one row per thread, no staging (only used if rows % RPB != 0).
__global__ __launch_bounds__(BLOCK) void affine_to_matrix_tail(
    const float* __restrict__ in, float* __restrict__ out,
    size_t rowStart, size_t nRows) {
    size_t i = rowStart + blockIdx.x * (size_t)BLOCK + threadIdx.x;
    if (i >= nRows) return;
    const float* v = in + i * 6;
    float sx, cx, sy, cy, sz, cz;
    __sincosf(v[3], &sx, &cx);
    __sincosf(v[4], &sy, &cy);
    __sincosf(v[5], &sz, &cz);
    float sxsy = sx * sy, cxsy = cx * sy;
    float* m = out + i * 12;
    m[0] = cy * cz - 1.0f;      m[1] = -cy * sz;                   m[2]  = sy;              m[3]  = v[0];
    m[4] = cx * sz + sxsy * cz; m[5] = cx * cz - sxsy * sz - 1.0f; m[6]  = -sx * cy;        m[7]  = v[1];
    m[8] = sx * sz - cxsy * cz; m[9] = sx * cz + cxsy * sz;        m[10] = cx * cy - 1.0f;  m[11] = v[2];
}

extern "C" void kernel_launch(void* const* d_in, const int* in_sizes, int n_in,
                              void* d_out, int out_size, void* d_ws, size_t ws_size,
                              hipStream_t stream) {
    const float* in = (const float*)d_in[0];
    float* out = (float*)d_out;
    size_t rows = (size_t)in_sizes[0] / 6;   // 4194304
    size_t fullBlocks = rows / RPB;          // 16384 (exact for this B)
    if (fullBlocks) {
        affine_to_matrix_staged<<<(unsigned)fullBlocks, BLOCK, 0, stream>>>(in, out);
    }
    size_t rem = rows - fullBlocks * RPB;
    if (rem) {
        unsigned tailGrid = (unsigned)((rem + BLOCK - 1) / BLOCK);
        affine_to_matrix_tail<<<tailGrid, BLOCK, 0, stream>>>(in, out, fullBlocks * RPB, rows);
    }
}

// Round 7
// 48.008 us; speedup vs baseline: 1.0959x; 1.0959x over previous
//
#include <hip/hip_runtime.h>

// B rows; input row: [tx, ty, tz, ax, ay, az] (f32)
// output row (12 f32): [M00-1, M01, M02, tx, M10, M11-1, M12, ty, M20, M21, M22-1, tz]
// where M = Rx(ax) @ Ry(ay) @ Rz(az), expanded in closed form.
//
// Round-5 winner (50.86 us) + nontemporal STORES only (single-variable A/B).
//   P1 : 3x float4/thread global->LDS linear          (conflict-free)
//   P2a: 3x b128 read own rows (stride 48B)           (~free, 2-way)
//   P2b: 6x b128 write, XOR-swizzled float4 index     (conflict-free)
//   P3 : 6x float4/thread swizzled LDS read -> nt global store

#define BLOCK 256
#define RPB   512   // rows per block (2 per thread)

typedef float f32x4 __attribute__((ext_vector_type(4)));

__device__ __forceinline__ int swz(int i) { return i ^ ((i >> 3) & 7); }

__global__ __launch_bounds__(BLOCK) void affine_to_matrix_staged(
    const float* __restrict__ in, float* __restrict__ out) {
    __shared__ float s_in[RPB * 6];    // 12 KB
    __shared__ float s_out[RPB * 12];  // 24 KB

    const int tid = threadIdx.x;
    const size_t rowBase = (size_t)blockIdx.x * RPB;
    const float4* gin  = reinterpret_cast<const float4*>(in  + rowBase * 6);
    f32x4*        gout = reinterpret_cast<f32x4*>(out + rowBase * 12);

    // P1: coalesced global -> LDS (linear)
    float4* s_in4 = reinterpret_cast<float4*>(s_in);
    #pragma unroll
    for (int k = 0; k < 3; ++k) {
        int g = tid + k * BLOCK;
        s_in4[g] = gin[g];
    }
    __syncthreads();

    // P2a: read own two rows; P2b: compute + swizzled LDS write
    const float4* myin = reinterpret_cast<const float4*>(s_in + tid * 12);
    float4 a = myin[0], b = myin[1], c = myin[2];
    float r[12] = {a.x, a.y, a.z, a.w, b.x, b.y, b.z, b.w, c.x, c.y, c.z, c.w};
    float4* s_out4 = reinterpret_cast<float4*>(s_out);
    #pragma unroll
    for (int k2 = 0; k2 < 2; ++k2) {
        const float* v = r + k2 * 6;
        float sx, cx, sy, cy, sz, cz;
        __sincosf(v[3], &sx, &cx);
        __sincosf(v[4], &sy, &cy);
        __sincosf(v[5], &sz, &cz);
        float sxsy = sx * sy;
        float cxsy = cx * sy;
        int base = tid * 6 + k2 * 3;
        s_out4[swz(base + 0)] = make_float4(cy * cz - 1.0f,      -cy * sz,                    sy,             v[0]);
        s_out4[swz(base + 1)] = make_float4(cx * sz + sxsy * cz, cx * cz - sxsy * sz - 1.0f,  -sx * cy,       v[1]);
        s_out4[swz(base + 2)] = make_float4(sx * sz - cxsy * cz, sx * cz + cxsy * sz,         cx * cy - 1.0f, v[2]);
    }
    __syncthreads();

    // P3: swizzled LDS read -> coalesced nontemporal global store
    const f32x4* s_outv = reinterpret_cast<const f32x4*>(s_out);
    #pragma unroll
    for (int k = 0; k < 6; ++k) {
        int g = tid + k * BLOCK;
        __builtin_nontemporal_store(s_outv[swz(g)], &gout[g]);
    }
}

// Tail path: one row per thread, no staging (only used if rows % RPB != 0).
__global__ __launch_bounds__(BLOCK) void affine_to_matrix_tail(
    const float* __restrict__ in, float* __restrict__ out,
    size_t rowStart, size_t nRows) {
    size_t i = rowStart + blockIdx.x * (size_t)BLOCK + threadIdx.x;
    if (i >= nRows) return;
    const float* v = in + i * 6;
    float sx, cx, sy, cy, sz, cz;
    __sincosf(v[3], &sx, &cx);
    __sincosf(v[4], &sy, &cy);
    __sincosf(v[5], &sz, &cz);
    float sxsy = sx * sy, cxsy = cx * sy;
    float* m = out + i * 12;
    m[0] = cy * cz - 1.0f;      m[1] = -cy * sz;                   m[2]  = sy;              m[3]  = v[0];
    m[4] = cx * sz + sxsy * cz; m[5] = cx * cz - sxsy * sz - 1.0f; m[6]  = -sx * cy;        m[7]  = v[1];
    m[8] = sx * sz - cxsy * cz; m[9] = sx * cz + cxsy * sz;        m[10] = cx * cy - 1.0f;  m[11] = v[2];
}

extern "C" void kernel_launch(void* const* d_in, const int* in_sizes, int n_in,
                              void* d_out, int out_size, void* d_ws, size_t ws_size,
                              hipStream_t stream) {
    const float* in = (const float*)d_in[0];
    float* out = (float*)d_out;
    size_t rows = (size_t)in_sizes[0] / 6;   // 4194304
    size_t fullBlocks = rows / RPB;          // 8192 (exact for this B)
    if (fullBlocks) {
        affine_to_matrix_staged<<<(unsigned)fullBlocks, BLOCK, 0, stream>>>(in, out);
    }
    size_t rem = rows - fullBlocks * RPB;
    if (rem) {
        unsigned tailGrid = (unsigned)((rem + BLOCK - 1) / BLOCK);
        affine_to_matrix_tail<<<tailGrid, BLOCK, 0, stream>>>(in, out, fullBlocks * RPB, rows);
    }
}